// Round 6
// baseline (323.898 us; speedup 1.0000x reference)
//
#include <hip/hip_runtime.h>
#include <math.h>

#define N      128
#define LOGN   7
#define NSQ    (N * N)          // 16384
#define VOL    (N * N * N)      // 2097152
#define NSHELL 64
#define BTOT   8
#define FPI    3.14159265358979323846f

#define TL     16               // lines per tile (FFT passes)
#define TP     (TL + 1)         // padded row stride in float2

// ---------------------------------------------------------------------------
// 16 simultaneous 128-point Stockham FFTs over an LDS tile, radix-4 fused:
// stages (0,1),(2,3),(4,5) in registers (one LDS round each) + radix-2 s=6.
// (verified rounds 5)
// ---------------------------------------------------------------------------
__device__ inline float2* fft16(float2* A, float2* B, int t) {
    const int j5 = t & 31;           // butterfly-4 index
    const int lg = (t >> 5) << 1;    // 2 lines per thread
    float2* src = A;
    float2* dst = B;
#pragma unroll
    for (int s = 0; s < 6; s += 2) {
        const int Ns = 1 << s;
        const int m  = j5 & (Ns - 1);
        const int cc = j5 >> s;
        const int e0 = (cc << (s + 2)) + m;      // c*4Ns + m
        float s2, c2;
        __sincosf(-FPI * (float)m / (float)(2 * Ns), &s2, &c2);
        const float cw = c2 * c2 - s2 * s2;      // w = w2m^2
        const float sw = 2.f * c2 * s2;
        __syncthreads();
#pragma unroll
        for (int l = 0; l < 2; ++l) {
            const int line = lg + l;
            const float2 a  = src[ j5       * TP + line];
            const float2 cv = src[(j5 + 32) * TP + line];
            const float2 b  = src[(j5 + 64) * TP + line];
            const float2 d  = src[(j5 + 96) * TP + line];
            const float wbx = b.x * cw - b.y * sw, wby = b.x * sw + b.y * cw;
            const float wdx = d.x * cw - d.y * sw, wdy = d.x * sw + d.y * cw;
            const float Apx = a.x + wbx, Apy = a.y + wby;
            const float Amx = a.x - wbx, Amy = a.y - wby;
            const float Bpx = cv.x + wdx, Bpy = cv.y + wdy;
            const float Bmx = cv.x - wdx, Bmy = cv.y - wdy;
            const float t0x = Bpx * c2 - Bpy * s2, t0y = Bpx * s2 + Bpy * c2;
            const float t1x = Bmx * c2 - Bmy * s2, t1y = Bmx * s2 + Bmy * c2;
            dst[(e0)          * TP + line] = make_float2(Apx + t0x, Apy + t0y);
            dst[(e0 + Ns)     * TP + line] = make_float2(Amx + t1y, Amy - t1x);
            dst[(e0 + 2 * Ns) * TP + line] = make_float2(Apx - t0x, Apy - t0y);
            dst[(e0 + 3 * Ns) * TP + line] = make_float2(Amx - t1y, Amy + t1x);
        }
        float2* tmp = src; src = dst; dst = tmp;
    }
    // final radix-2 stage, s=6
    {
        const int m   = t & 63;
        const int grp = (t >> 6) << 2;
        float sw, cw;
        __sincosf(-FPI * (float)m / 64.f, &sw, &cw);
        __syncthreads();
#pragma unroll
        for (int l = 0; l < 4; ++l) {
            const int line = grp + l;
            const float2 v0 = src[m * TP + line];
            const float2 v1 = src[(m + 64) * TP + line];
            const float wx = v1.x * cw - v1.y * sw;
            const float wy = v1.x * sw + v1.y * cw;
            dst[m * TP + line]        = make_float2(v0.x + wx, v0.y + wy);
            dst[(m + 64) * TP + line] = make_float2(v0.x - wx, v0.y - wy);
        }
    }
    __syncthreads();
    return dst;
}

// ---------------------------------------------------------------------------
// Pass 1: pack Z = ref + i*pred and FFT along z (contiguous axis).
// ---------------------------------------------------------------------------
__global__ __launch_bounds__(256) void k_fftz_pack(const float* __restrict__ ref,
                                                   const float* __restrict__ pred,
                                                   float2* __restrict__ Z, int b0) {
    __shared__ float2 A[N * TP], B[N * TP];
    const int t  = threadIdx.x;
    const int yt = blockIdx.x & 7;
    const int x  = (blockIdx.x >> 3) & (N - 1);
    const int bl = blockIdx.x >> 10;
    const size_t inbase = (size_t)(b0 + bl) * VOL + (size_t)x * NSQ + (size_t)yt * TL * N;
    const size_t zbase  = (size_t)bl * VOL + (size_t)x * NSQ + (size_t)yt * TL * N;
#pragma unroll
    for (int i = 0; i < 8; ++i) {
        const int elem = i * 256 + t;
        const int z = elem & (N - 1);
        const int j = elem >> LOGN;
        A[z * TP + j] = make_float2(ref[inbase + elem], pred[inbase + elem]);
    }
    float2* res = fft16(A, B, t);
#pragma unroll
    for (int i = 0; i < 8; ++i) {
        const int elem = i * 256 + t;
        const int z = elem & (N - 1);
        const int j = elem >> LOGN;
        Z[zbase + elem] = res[z * TP + j];
    }
}

// ---------------------------------------------------------------------------
// Pass 2: FFT along y (stride N), 16-z tiles.
// ---------------------------------------------------------------------------
__global__ __launch_bounds__(256) void k_ffty(float2* __restrict__ Z) {
    __shared__ float2 A[N * TP], B[N * TP];
    const int t   = threadIdx.x;
    const int zt  = blockIdx.x & 7;
    const int mid = (blockIdx.x >> 3) & (N - 1);
    const int bl  = blockIdx.x >> 10;
    const size_t base = (size_t)bl * VOL + (size_t)mid * NSQ + (size_t)zt * TL;
#pragma unroll
    for (int i = 0; i < 8; ++i) {
        const int elem = i * 256 + t;
        const int zz = elem & (TL - 1);
        const int j  = elem >> 4;
        A[j * TP + zz] = Z[base + (size_t)j * N + zz];
    }
    float2* res = fft16(A, B, t);
#pragma unroll
    for (int i = 0; i < 8; ++i) {
        const int elem = i * 256 + t;
        const int zz = elem & (TL - 1);
        const int j  = elem >> 4;
        Z[base + (size_t)j * N + zz] = res[j * TP + zz];
    }
}

// ---------------------------------------------------------------------------
// Exact floor(sqrt(r2)) for integer r2.
// ---------------------------------------------------------------------------
__device__ inline int isqrt_i(int r2) {
    int s = (int)sqrtf((float)r2);
    s -= (s * s > r2);
    s += ((s + 1) * (s + 1) <= r2);
    return s;
}

// ---------------------------------------------------------------------------
// Pass 3 (fused): x-FFT + Hermitian-pair shell reduction.
// Block = (batch, y, z-run of 8). Tile lines 0..7 = (y, z0+zz); lines 8..15 =
// conjugate partners (my, (128-z0-zz)&127). After the x-FFT, point k=(x,y,z)
// has Z(k) = res[x*TP + l] and Z(-k) = res[mx*TP + 8 + l] -> reduce locally.
// Pair-once weights: z=64 plane dropped (fz^2=4096 -> s>=64, contributes 0);
// z in [1,63]: weight 2 (partner z in [65,127] never enumerated);
// z = 0 plane: weight 1 (both pair halves enumerated, incl. self-pairs).
// Sum of weights = VOL - 16384 (the dropped z=64 plane) = exact cover.
// Block-uniform sphere skip: min r^2 over tile = fy^2 + z0^2.
// All global loads unconditional -> full MLP (no divergent-gated loads).
// ---------------------------------------------------------------------------
__global__ __launch_bounds__(256) void k_fftx_reduce(const float2* __restrict__ Z,
                                                     float* __restrict__ accum, int b0) {
    const int t  = threadIdx.x;
    const int zr = blockIdx.x & 7;
    const int y  = (blockIdx.x >> 3) & (N - 1);
    const int bl = blockIdx.x >> 10;
    const int z0 = zr * 8;
    const int fy = y - ((y >= 64) ? N : 0);

    if (fy * fy + z0 * z0 >= 4096) return;   // whole tile outside sphere

    __shared__ float2 A[N * TP], B[N * TP];
    __shared__ float sh[4 * 193];
    for (int i = t; i < 4 * 193; i += 256) sh[i] = 0.f;
    // (visibility of sh-init guaranteed by the syncs inside fft16)

    const int my = (N - y) & (N - 1);
    const size_t zb    = (size_t)bl * VOL;
    const size_t baseA = zb + (size_t)y  * N + z0;   // + j*NSQ + zz
    const size_t baseB = zb + (size_t)my * N;        // + j*NSQ + mz
#pragma unroll
    for (int i = 0; i < 4; ++i) {                    // A-group: lines (y, z0+zz)
        const int elem = i * 256 + t;
        const int zz = elem & 7;
        const int j  = elem >> 3;
        A[j * TP + zz] = Z[baseA + (size_t)j * NSQ + zz];
    }
#pragma unroll
    for (int i = 0; i < 4; ++i) {                    // B-group: partner lines
        const int elem = i * 256 + t;
        const int zz = elem & 7;
        const int j  = elem >> 3;
        const int mz = (N - z0 - zz) & (N - 1);
        A[j * TP + 8 + zz] = Z[baseB + (size_t)j * NSQ + mz];
    }

    float2* res = fft16(A, B, t);

    // reduce: thread -> pair l = t>>5, x = x0..x0+3 consecutive (run-length)
    const int l  = t >> 5;
    const int x0 = (t & 31) * 4;
    const int z  = z0 + l;                           // fz = z (z <= 63)
    const float w = (z == 0) ? 1.f : 2.f;
    const int ryz = fy * fy + z * z;
    float* bins = sh + (t & 3) * 193;

    float aC = 0.f, aP1 = 0.f, aP2 = 0.f;
    int cs = -1;
#pragma unroll
    for (int i = 0; i < 4; ++i) {
        const int x  = x0 + i;
        const int fx = x - ((x >= 64) ? N : 0);
        const int s  = isqrt_i(fx * fx + ryz);
        if (s != cs) {
            if (cs >= 0 && cs < NSHELL) {
                atomicAdd(&bins[cs * 3 + 0], w * aC);
                atomicAdd(&bins[cs * 3 + 1], w * aP1);
                atomicAdd(&bins[cs * 3 + 2], w * aP2);
            }
            cs = s; aC = 0.f; aP1 = 0.f; aP2 = 0.f;
        }
        if (s < NSHELL) {
            const int mx = (N - x) & (N - 1);
            const float2 Av = res[x  * TP + l];
            const float2 Bv = res[mx * TP + 8 + l];
            const float F1x = 0.5f * (Av.x + Bv.x);
            const float F1y = 0.5f * (Av.y - Bv.y);
            const float F2x = 0.5f * (Av.y + Bv.y);
            const float F2y = 0.5f * (Bv.x - Av.x);
            aC  += F1x * F2x + F1y * F2y;
            aP1 += F1x * F1x + F1y * F1y;
            aP2 += F2x * F2x + F2y * F2y;
        }
    }
    if (cs >= 0 && cs < NSHELL) {
        atomicAdd(&bins[cs * 3 + 0], w * aC);
        atomicAdd(&bins[cs * 3 + 1], w * aP1);
        atomicAdd(&bins[cs * 3 + 2], w * aP2);
    }
    __syncthreads();

    float* acc = accum + (size_t)(b0 + bl) * (NSHELL * 3);
    for (int i = t; i < NSHELL * 3; i += 256) {
        const float v = sh[i] + sh[193 + i] + sh[2 * 193 + i] + sh[3 * 193 + i];
        atomicAdd(&acc[i], v);
    }
}

// ---------------------------------------------------------------------------
// Pass 4: FSC + loss. 512 threads = 8 batches x 64 shells.
// ---------------------------------------------------------------------------
__global__ __launch_bounds__(512) void k_final(const float* __restrict__ accum,
                                               float* __restrict__ out) {
    __shared__ float red[8];
    const int tid = threadIdx.x;
    const float* a = accum + (size_t)tid * 3;
    const float fsc = a[0] / (sqrtf(a[1] * a[2]) + 1e-8f);
    float v = fsc * fsc;
#pragma unroll
    for (int off = 32; off > 0; off >>= 1) v += __shfl_down(v, off);
    if ((tid & 63) == 0) red[tid >> 6] = v;
    __syncthreads();
    if (tid == 0) {
        float ssum = 0.f;
#pragma unroll
        for (int i = 0; i < 8; ++i) ssum += red[i];
        out[0] = 1.0f - ssum / 512.0f;
    }
}

extern "C" void kernel_launch(void* const* d_in, const int* in_sizes, int n_in,
                              void* d_out, int out_size, void* d_ws, size_t ws_size,
                              hipStream_t stream) {
    const float* ref  = (const float*)d_in[0];
    const float* pred = (const float*)d_in[1];
    float* out = (float*)d_out;

    char*   ws    = (char*)d_ws;
    float*  accum = (float*)ws;
    float2* Zbuf  = (float2*)(ws + 8192);

    const size_t zbytes = (size_t)VOL * sizeof(float2);
    int cap = 1;
    if (ws_size > 8192) {
        size_t c = (ws_size - 8192) / zbytes;
        cap = (c < 1) ? 1 : (c > BTOT ? BTOT : (int)c);
    }

    hipMemsetAsync(accum, 0, BTOT * NSHELL * 3 * sizeof(float), stream);

    for (int b0 = 0; b0 < BTOT; b0 += cap) {
        const int nb = (BTOT - b0 < cap) ? (BTOT - b0) : cap;
        const int nblk = nb * 1024;
        k_fftz_pack<<<nblk, 256, 0, stream>>>(ref, pred, Zbuf, b0);
        k_ffty<<<nblk, 256, 0, stream>>>(Zbuf);
        k_fftx_reduce<<<nblk, 256, 0, stream>>>(Zbuf, accum, b0);
    }
    k_final<<<1, 512, 0, stream>>>(accum, out);
}

// Round 7
// 322.942 us; speedup vs baseline: 1.0030x; 1.0030x over previous
//
#include <hip/hip_runtime.h>
#include <math.h>

#define N      128
#define LOGN   7
#define NSQ    (N * N)          // 16384
#define VOL    (N * N * N)      // 2097152
#define NSHELL 64
#define BTOT   8
#define FPI    3.14159265358979323846f

#define TL     16               // lines per tile (FFT passes)
#define TP     (TL + 1)         // padded row stride in float2

// ---------------------------------------------------------------------------
// 16 simultaneous 128-point Stockham FFTs, IN PLACE in a single LDS buffer:
// each radix-4 stage reads its 4 points into registers, barriers, then
// writes results back to the same buffer (read set != write set per thread,
// but collectively both cover 0..127 -> barrier between makes it safe).
// Halves LDS vs double-buffer -> 8 blocks/CU instead of 4.
// Math identical to the round-5/6 verified radix-4 fused Stockham.
// ---------------------------------------------------------------------------
__device__ inline void fft16_ip(float2* S, int t) {
    const int j5 = t & 31;           // butterfly-4 index
    const int lg = (t >> 5) << 1;    // 2 lines per thread
#pragma unroll
    for (int s = 0; s < 6; s += 2) {
        const int Ns = 1 << s;
        const int m  = j5 & (Ns - 1);
        const int cc = j5 >> s;
        const int e0 = (cc << (s + 2)) + m;      // c*4Ns + m
        float s2, c2;
        __sincosf(-FPI * (float)m / (float)(2 * Ns), &s2, &c2);
        const float cw = c2 * c2 - s2 * s2;      // w = w2m^2
        const float sw = 2.f * c2 * s2;
        __syncthreads();                         // fill / prev-stage writes
        float2 a[2], cv[2], b[2], d[2];
#pragma unroll
        for (int l = 0; l < 2; ++l) {
            a[l]  = S[ j5       * TP + lg + l];
            cv[l] = S[(j5 + 32) * TP + lg + l];
            b[l]  = S[(j5 + 64) * TP + lg + l];
            d[l]  = S[(j5 + 96) * TP + lg + l];
        }
        __syncthreads();                         // all reads done
#pragma unroll
        for (int l = 0; l < 2; ++l) {
            const int line = lg + l;
            const float wbx = b[l].x * cw - b[l].y * sw, wby = b[l].x * sw + b[l].y * cw;
            const float wdx = d[l].x * cw - d[l].y * sw, wdy = d[l].x * sw + d[l].y * cw;
            const float Apx = a[l].x + wbx, Apy = a[l].y + wby;
            const float Amx = a[l].x - wbx, Amy = a[l].y - wby;
            const float Bpx = cv[l].x + wdx, Bpy = cv[l].y + wdy;
            const float Bmx = cv[l].x - wdx, Bmy = cv[l].y - wdy;
            const float t0x = Bpx * c2 - Bpy * s2, t0y = Bpx * s2 + Bpy * c2;
            const float t1x = Bmx * c2 - Bmy * s2, t1y = Bmx * s2 + Bmy * c2;
            S[(e0)          * TP + line] = make_float2(Apx + t0x, Apy + t0y);
            S[(e0 + Ns)     * TP + line] = make_float2(Amx + t1y, Amy - t1x);
            S[(e0 + 2 * Ns) * TP + line] = make_float2(Apx - t0x, Apy - t0y);
            S[(e0 + 3 * Ns) * TP + line] = make_float2(Amx - t1y, Amy + t1x);
        }
    }
    // final radix-2 stage, s=6 (pairs m, m+64), in place
    {
        const int m   = t & 63;
        const int grp = (t >> 6) << 2;
        float sw, cw;
        __sincosf(-FPI * (float)m / 64.f, &sw, &cw);
        __syncthreads();
        float2 v0[4], v1[4];
#pragma unroll
        for (int l = 0; l < 4; ++l) {
            v0[l] = S[ m       * TP + grp + l];
            v1[l] = S[(m + 64) * TP + grp + l];
        }
        __syncthreads();
#pragma unroll
        for (int l = 0; l < 4; ++l) {
            const float wx = v1[l].x * cw - v1[l].y * sw;
            const float wy = v1[l].x * sw + v1[l].y * cw;
            S[ m       * TP + grp + l] = make_float2(v0[l].x + wx, v0[l].y + wy);
            S[(m + 64) * TP + grp + l] = make_float2(v0[l].x - wx, v0[l].y - wy);
        }
    }
    __syncthreads();                             // results visible to all
}

// ---------------------------------------------------------------------------
// Pass 1: pack Z = ref + i*pred and FFT along z. float4-vectorized I/O.
// ---------------------------------------------------------------------------
__global__ __launch_bounds__(256) void k_fftz_pack(const float* __restrict__ ref,
                                                   const float* __restrict__ pred,
                                                   float2* __restrict__ Z, int b0) {
    __shared__ float2 S[N * TP];
    const int t  = threadIdx.x;
    const int yt = blockIdx.x & 7;
    const int x  = (blockIdx.x >> 3) & (N - 1);
    const int bl = blockIdx.x >> 10;
    const size_t inbase = (size_t)(b0 + bl) * VOL + (size_t)x * NSQ + (size_t)yt * TL * N;
    const size_t zbase  = (size_t)bl * VOL + (size_t)x * NSQ + (size_t)yt * TL * N;
    const float4* r4 = (const float4*)(ref + inbase);
    const float4* p4 = (const float4*)(pred + inbase);
#pragma unroll
    for (int i = 0; i < 2; ++i) {
        const int idx = i * 256 + t;             // 512 float4 = 2048 floats
        const float4 rv = r4[idx];
        const float4 pv = p4[idx];
        const int elem = idx * 4;
        const int z = elem & (N - 1);
        const int j = elem >> LOGN;
        S[(z + 0) * TP + j] = make_float2(rv.x, pv.x);
        S[(z + 1) * TP + j] = make_float2(rv.y, pv.y);
        S[(z + 2) * TP + j] = make_float2(rv.z, pv.z);
        S[(z + 3) * TP + j] = make_float2(rv.w, pv.w);
    }
    fft16_ip(S, t);
    float4* z4 = (float4*)(Z + zbase);
#pragma unroll
    for (int i = 0; i < 4; ++i) {
        const int idx = i * 256 + t;             // 1024 float4 = 2048 float2
        const int elem = idx * 2;
        const int z = elem & (N - 1);
        const int j = elem >> LOGN;
        const float2 u0 = S[ z      * TP + j];
        const float2 u1 = S[(z + 1) * TP + j];
        z4[idx] = make_float4(u0.x, u0.y, u1.x, u1.y);
    }
}

// ---------------------------------------------------------------------------
// Pass 2: FFT along y (stride N), 16-z tiles. float4-vectorized I/O
// (8 lanes cover 128 B contiguous per row).
// ---------------------------------------------------------------------------
__global__ __launch_bounds__(256) void k_ffty(float2* __restrict__ Z) {
    __shared__ float2 S[N * TP];
    const int t   = threadIdx.x;
    const int zt  = blockIdx.x & 7;
    const int mid = (blockIdx.x >> 3) & (N - 1);
    const int bl  = blockIdx.x >> 10;
    const size_t base = (size_t)bl * VOL + (size_t)mid * NSQ + (size_t)zt * TL;
#pragma unroll
    for (int i = 0; i < 4; ++i) {
        const int idx = i * 256 + t;             // 1024 float4: 128 rows x 8
        const int j = idx >> 3;                  // y coord (row)
        const int q = (idx & 7) * 2;             // zz pair
        const float4 v = *(const float4*)&Z[base + (size_t)j * N + q];
        S[j * TP + q]     = make_float2(v.x, v.y);
        S[j * TP + q + 1] = make_float2(v.z, v.w);
    }
    fft16_ip(S, t);
#pragma unroll
    for (int i = 0; i < 4; ++i) {
        const int idx = i * 256 + t;
        const int j = idx >> 3;
        const int q = (idx & 7) * 2;
        const float2 u0 = S[j * TP + q];
        const float2 u1 = S[j * TP + q + 1];
        *(float4*)&Z[base + (size_t)j * N + q] = make_float4(u0.x, u0.y, u1.x, u1.y);
    }
}

// ---------------------------------------------------------------------------
// Exact floor(sqrt(r2)) for integer r2.
// ---------------------------------------------------------------------------
__device__ inline int isqrt_i(int r2) {
    int s = (int)sqrtf((float)r2);
    s -= (s * s > r2);
    s += ((s + 1) * (s + 1) <= r2);
    return s;
}

// ---------------------------------------------------------------------------
// Pass 3 (fused): x-FFT + Hermitian-pair shell reduction (round-6 verified
// pairing/weights), now single-LDS-buffer + 2 bin copies -> 8 blocks/CU.
// Tile lines 0..7 = (y, z0+zz); lines 8..15 = partners (my, (128-z0-zz)&127).
// Weights: z=64 plane dropped (s>=64); z in [1,63] w=2; z=0 w=1.
// ---------------------------------------------------------------------------
__global__ __launch_bounds__(256) void k_fftx_reduce(const float2* __restrict__ Z,
                                                     float* __restrict__ accum, int b0) {
    const int t  = threadIdx.x;
    const int zr = blockIdx.x & 7;
    const int y  = (blockIdx.x >> 3) & (N - 1);
    const int bl = blockIdx.x >> 10;
    const int z0 = zr * 8;
    const int fy = y - ((y >= 64) ? N : 0);

    if (fy * fy + z0 * z0 >= 4096) return;   // whole tile outside sphere

    __shared__ float2 S[N * TP];
    __shared__ float sh[2 * 193];
    for (int i = t; i < 2 * 193; i += 256) sh[i] = 0.f;
    // (visibility guaranteed by syncs inside fft16_ip)

    const int my = (N - y) & (N - 1);
    const size_t zb    = (size_t)bl * VOL;
    const size_t baseA = zb + (size_t)y  * N + z0;   // + j*NSQ + zz
    const size_t baseB = zb + (size_t)my * N;        // + j*NSQ + mz
    // A-group, float4 (rows have 8 consecutive float2 starting at z0):
#pragma unroll
    for (int i = 0; i < 2; ++i) {
        const int idx = i * 256 + t;                 // 512 float4: 128 rows x 4
        const int j = idx >> 2;
        const int q = (idx & 3) * 2;
        const float4 v = *(const float4*)&Z[baseA + (size_t)j * NSQ + q];
        S[j * TP + q]     = make_float2(v.x, v.y);
        S[j * TP + q + 1] = make_float2(v.z, v.w);
    }
    // B-group, scalar (reversed order within 64-B segments still coalesces):
#pragma unroll
    for (int i = 0; i < 4; ++i) {
        const int elem = i * 256 + t;                // 1024: 128 rows x 8
        const int zz = elem & 7;
        const int j  = elem >> 3;
        const int mz = (N - z0 - zz) & (N - 1);
        S[j * TP + 8 + zz] = Z[baseB + (size_t)j * NSQ + mz];
    }

    fft16_ip(S, t);

    // reduce: thread -> pair line l = t>>5, x = x0..x0+3 (run-length flush)
    const int l  = t >> 5;
    const int x0 = (t & 31) * 4;
    const int z  = z0 + l;                           // fz = z (z <= 63)
    const float w = (z == 0) ? 1.f : 2.f;
    const int ryz = fy * fy + z * z;
    float* bins = sh + (t & 1) * 193;

    float aC = 0.f, aP1 = 0.f, aP2 = 0.f;
    int cs = -1;
#pragma unroll
    for (int i = 0; i < 4; ++i) {
        const int x  = x0 + i;
        const int fx = x - ((x >= 64) ? N : 0);
        const int s  = isqrt_i(fx * fx + ryz);
        if (s != cs) {
            if (cs >= 0 && cs < NSHELL) {
                atomicAdd(&bins[cs * 3 + 0], w * aC);
                atomicAdd(&bins[cs * 3 + 1], w * aP1);
                atomicAdd(&bins[cs * 3 + 2], w * aP2);
            }
            cs = s; aC = 0.f; aP1 = 0.f; aP2 = 0.f;
        }
        if (s < NSHELL) {
            const int mx = (N - x) & (N - 1);
            const float2 Av = S[x  * TP + l];
            const float2 Bv = S[mx * TP + 8 + l];
            const float F1x = 0.5f * (Av.x + Bv.x);
            const float F1y = 0.5f * (Av.y - Bv.y);
            const float F2x = 0.5f * (Av.y + Bv.y);
            const float F2y = 0.5f * (Bv.x - Av.x);
            aC  += F1x * F2x + F1y * F2y;
            aP1 += F1x * F1x + F1y * F1y;
            aP2 += F2x * F2x + F2y * F2y;
        }
    }
    if (cs >= 0 && cs < NSHELL) {
        atomicAdd(&bins[cs * 3 + 0], w * aC);
        atomicAdd(&bins[cs * 3 + 1], w * aP1);
        atomicAdd(&bins[cs * 3 + 2], w * aP2);
    }
    __syncthreads();

    float* acc = accum + (size_t)(b0 + bl) * (NSHELL * 3);
    for (int i = t; i < NSHELL * 3; i += 256) {
        atomicAdd(&acc[i], sh[i] + sh[193 + i]);
    }
}

// ---------------------------------------------------------------------------
// Pass 4: FSC + loss. 512 threads = 8 batches x 64 shells.
// ---------------------------------------------------------------------------
__global__ __launch_bounds__(512) void k_final(const float* __restrict__ accum,
                                               float* __restrict__ out) {
    __shared__ float red[8];
    const int tid = threadIdx.x;
    const float* a = accum + (size_t)tid * 3;
    const float fsc = a[0] / (sqrtf(a[1] * a[2]) + 1e-8f);
    float v = fsc * fsc;
#pragma unroll
    for (int off = 32; off > 0; off >>= 1) v += __shfl_down(v, off);
    if ((tid & 63) == 0) red[tid >> 6] = v;
    __syncthreads();
    if (tid == 0) {
        float ssum = 0.f;
#pragma unroll
        for (int i = 0; i < 8; ++i) ssum += red[i];
        out[0] = 1.0f - ssum / 512.0f;
    }
}

extern "C" void kernel_launch(void* const* d_in, const int* in_sizes, int n_in,
                              void* d_out, int out_size, void* d_ws, size_t ws_size,
                              hipStream_t stream) {
    const float* ref  = (const float*)d_in[0];
    const float* pred = (const float*)d_in[1];
    float* out = (float*)d_out;

    char*   ws    = (char*)d_ws;
    float*  accum = (float*)ws;
    float2* Zbuf  = (float2*)(ws + 8192);

    const size_t zbytes = (size_t)VOL * sizeof(float2);
    int cap = 1;
    if (ws_size > 8192) {
        size_t c = (ws_size - 8192) / zbytes;
        cap = (c < 1) ? 1 : (c > BTOT ? BTOT : (int)c);
    }

    hipMemsetAsync(accum, 0, BTOT * NSHELL * 3 * sizeof(float), stream);

    for (int b0 = 0; b0 < BTOT; b0 += cap) {
        const int nb = (BTOT - b0 < cap) ? (BTOT - b0) : cap;
        const int nblk = nb * 1024;
        k_fftz_pack<<<nblk, 256, 0, stream>>>(ref, pred, Zbuf, b0);
        k_ffty<<<nblk, 256, 0, stream>>>(Zbuf);
        k_fftx_reduce<<<nblk, 256, 0, stream>>>(Zbuf, accum, b0);
    }
    k_final<<<1, 512, 0, stream>>>(accum, out);
}

// Round 8
// 318.324 us; speedup vs baseline: 1.0175x; 1.0145x over previous
//
#include <hip/hip_runtime.h>
#include <math.h>

#define N      128
#define LOGN   7
#define NSQ    (N * N)          // 16384
#define VOL    (N * N * N)      // 2097152
#define NSHELL 64
#define BTOT   8
#define NREP   32               // accumulator replicas (atomic-contention spread)
#define FPI    3.14159265358979323846f

#define TL     16               // lines per tile (FFT passes)
#define TP     (TL + 1)         // padded row stride in float2

// ---------------------------------------------------------------------------
// 16 simultaneous 128-point Stockham FFTs, in place in one LDS buffer
// (radix-4 fused stages + final radix-2; verified rounds 5-7).
// ---------------------------------------------------------------------------
__device__ inline void fft16_ip(float2* S, int t) {
    const int j5 = t & 31;           // butterfly-4 index
    const int lg = (t >> 5) << 1;    // 2 lines per thread
#pragma unroll
    for (int s = 0; s < 6; s += 2) {
        const int Ns = 1 << s;
        const int m  = j5 & (Ns - 1);
        const int cc = j5 >> s;
        const int e0 = (cc << (s + 2)) + m;      // c*4Ns + m
        float s2, c2;
        __sincosf(-FPI * (float)m / (float)(2 * Ns), &s2, &c2);
        const float cw = c2 * c2 - s2 * s2;      // w = w2m^2
        const float sw = 2.f * c2 * s2;
        __syncthreads();
        float2 a[2], cv[2], b[2], d[2];
#pragma unroll
        for (int l = 0; l < 2; ++l) {
            a[l]  = S[ j5       * TP + lg + l];
            cv[l] = S[(j5 + 32) * TP + lg + l];
            b[l]  = S[(j5 + 64) * TP + lg + l];
            d[l]  = S[(j5 + 96) * TP + lg + l];
        }
        __syncthreads();
#pragma unroll
        for (int l = 0; l < 2; ++l) {
            const int line = lg + l;
            const float wbx = b[l].x * cw - b[l].y * sw, wby = b[l].x * sw + b[l].y * cw;
            const float wdx = d[l].x * cw - d[l].y * sw, wdy = d[l].x * sw + d[l].y * cw;
            const float Apx = a[l].x + wbx, Apy = a[l].y + wby;
            const float Amx = a[l].x - wbx, Amy = a[l].y - wby;
            const float Bpx = cv[l].x + wdx, Bpy = cv[l].y + wdy;
            const float Bmx = cv[l].x - wdx, Bmy = cv[l].y - wdy;
            const float t0x = Bpx * c2 - Bpy * s2, t0y = Bpx * s2 + Bpy * c2;
            const float t1x = Bmx * c2 - Bmy * s2, t1y = Bmx * s2 + Bmy * c2;
            S[(e0)          * TP + line] = make_float2(Apx + t0x, Apy + t0y);
            S[(e0 + Ns)     * TP + line] = make_float2(Amx + t1y, Amy - t1x);
            S[(e0 + 2 * Ns) * TP + line] = make_float2(Apx - t0x, Apy - t0y);
            S[(e0 + 3 * Ns) * TP + line] = make_float2(Amx - t1y, Amy + t1x);
        }
    }
    {   // final radix-2 stage, s=6
        const int m   = t & 63;
        const int grp = (t >> 6) << 2;
        float sw, cw;
        __sincosf(-FPI * (float)m / 64.f, &sw, &cw);
        __syncthreads();
        float2 v0[4], v1[4];
#pragma unroll
        for (int l = 0; l < 4; ++l) {
            v0[l] = S[ m       * TP + grp + l];
            v1[l] = S[(m + 64) * TP + grp + l];
        }
        __syncthreads();
#pragma unroll
        for (int l = 0; l < 4; ++l) {
            const float wx = v1[l].x * cw - v1[l].y * sw;
            const float wy = v1[l].x * sw + v1[l].y * cw;
            S[ m       * TP + grp + l] = make_float2(v0[l].x + wx, v0[l].y + wy);
            S[(m + 64) * TP + grp + l] = make_float2(v0[l].x - wx, v0[l].y - wy);
        }
    }
    __syncthreads();
}

// ---------------------------------------------------------------------------
// Pass 1: pack Z = ref + i*pred and FFT along z. float4-vectorized I/O.
// ---------------------------------------------------------------------------
__global__ __launch_bounds__(256) void k_fftz_pack(const float* __restrict__ ref,
                                                   const float* __restrict__ pred,
                                                   float2* __restrict__ Z, int b0) {
    __shared__ float2 S[N * TP];
    const int t  = threadIdx.x;
    const int yt = blockIdx.x & 7;
    const int x  = (blockIdx.x >> 3) & (N - 1);
    const int bl = blockIdx.x >> 10;
    const size_t inbase = (size_t)(b0 + bl) * VOL + (size_t)x * NSQ + (size_t)yt * TL * N;
    const size_t zbase  = (size_t)bl * VOL + (size_t)x * NSQ + (size_t)yt * TL * N;
    const float4* r4 = (const float4*)(ref + inbase);
    const float4* p4 = (const float4*)(pred + inbase);
#pragma unroll
    for (int i = 0; i < 2; ++i) {
        const int idx = i * 256 + t;
        const float4 rv = r4[idx];
        const float4 pv = p4[idx];
        const int elem = idx * 4;
        const int z = elem & (N - 1);
        const int j = elem >> LOGN;
        S[(z + 0) * TP + j] = make_float2(rv.x, pv.x);
        S[(z + 1) * TP + j] = make_float2(rv.y, pv.y);
        S[(z + 2) * TP + j] = make_float2(rv.z, pv.z);
        S[(z + 3) * TP + j] = make_float2(rv.w, pv.w);
    }
    fft16_ip(S, t);
    float4* z4 = (float4*)(Z + zbase);
#pragma unroll
    for (int i = 0; i < 4; ++i) {
        const int idx = i * 256 + t;
        const int elem = idx * 2;
        const int z = elem & (N - 1);
        const int j = elem >> LOGN;
        const float2 u0 = S[ z      * TP + j];
        const float2 u1 = S[(z + 1) * TP + j];
        z4[idx] = make_float4(u0.x, u0.y, u1.x, u1.y);
    }
}

// ---------------------------------------------------------------------------
// Pass 2: FFT along y (stride N), 16-z tiles. float4-vectorized I/O.
// ---------------------------------------------------------------------------
__global__ __launch_bounds__(256) void k_ffty(float2* __restrict__ Z) {
    __shared__ float2 S[N * TP];
    const int t   = threadIdx.x;
    const int zt  = blockIdx.x & 7;
    const int mid = (blockIdx.x >> 3) & (N - 1);
    const int bl  = blockIdx.x >> 10;
    const size_t base = (size_t)bl * VOL + (size_t)mid * NSQ + (size_t)zt * TL;
#pragma unroll
    for (int i = 0; i < 4; ++i) {
        const int idx = i * 256 + t;
        const int j = idx >> 3;
        const int q = (idx & 7) * 2;
        const float4 v = *(const float4*)&Z[base + (size_t)j * N + q];
        S[j * TP + q]     = make_float2(v.x, v.y);
        S[j * TP + q + 1] = make_float2(v.z, v.w);
    }
    fft16_ip(S, t);
#pragma unroll
    for (int i = 0; i < 4; ++i) {
        const int idx = i * 256 + t;
        const int j = idx >> 3;
        const int q = (idx & 7) * 2;
        const float2 u0 = S[j * TP + q];
        const float2 u1 = S[j * TP + q + 1];
        *(float4*)&Z[base + (size_t)j * N + q] = make_float4(u0.x, u0.y, u1.x, u1.y);
    }
}

// ---------------------------------------------------------------------------
// Exact floor(sqrt(r2)) for integer r2.
// ---------------------------------------------------------------------------
__device__ inline int isqrt_i(int r2) {
    int s = (int)sqrtf((float)r2);
    s -= (s * s > r2);
    s += ((s + 1) * (s + 1) <= r2);
    return s;
}

// ---------------------------------------------------------------------------
// Pass 3 (fused): x-FFT + Hermitian-pair shell reduction (round-6 pairing).
// NEW this round: flush goes to accum replica (blockIdx & 31) and only
// covers shells [smin, 63] (smin = isqrt(fy^2+z0^2), lower shells provably
// untouched by this block) -- spreads the ~9 ns/op same-line global-atomic
// serialization that capped rounds 4-7.
// ---------------------------------------------------------------------------
__global__ __launch_bounds__(256) void k_fftx_reduce(const float2* __restrict__ Z,
                                                     float* __restrict__ accum, int b0) {
    const int t  = threadIdx.x;
    const int zr = blockIdx.x & 7;
    const int y  = (blockIdx.x >> 3) & (N - 1);
    const int bl = blockIdx.x >> 10;
    const int z0 = zr * 8;
    const int fy = y - ((y >= 64) ? N : 0);

    if (fy * fy + z0 * z0 >= 4096) return;   // whole tile outside sphere

    __shared__ float2 S[N * TP];
    __shared__ float sh[2 * 193];
    for (int i = t; i < 2 * 193; i += 256) sh[i] = 0.f;
    // (visibility guaranteed by syncs inside fft16_ip)

    const int my = (N - y) & (N - 1);
    const size_t zb    = (size_t)bl * VOL;
    const size_t baseA = zb + (size_t)y  * N + z0;
    const size_t baseB = zb + (size_t)my * N;
#pragma unroll
    for (int i = 0; i < 2; ++i) {                    // A-group: float4
        const int idx = i * 256 + t;
        const int j = idx >> 2;
        const int q = (idx & 3) * 2;
        const float4 v = *(const float4*)&Z[baseA + (size_t)j * NSQ + q];
        S[j * TP + q]     = make_float2(v.x, v.y);
        S[j * TP + q + 1] = make_float2(v.z, v.w);
    }
#pragma unroll
    for (int i = 0; i < 4; ++i) {                    // B-group: partner lines
        const int elem = i * 256 + t;
        const int zz = elem & 7;
        const int j  = elem >> 3;
        const int mz = (N - z0 - zz) & (N - 1);
        S[j * TP + 8 + zz] = Z[baseB + (size_t)j * NSQ + mz];
    }

    fft16_ip(S, t);

    // reduce: thread -> pair line l = t>>5, x = x0..x0+3 (run-length flush)
    const int l  = t >> 5;
    const int x0 = (t & 31) * 4;
    const int z  = z0 + l;
    const float w = (z == 0) ? 1.f : 2.f;
    const int ryz = fy * fy + z * z;
    float* bins = sh + (t & 1) * 193;

    float aC = 0.f, aP1 = 0.f, aP2 = 0.f;
    int cs = -1;
#pragma unroll
    for (int i = 0; i < 4; ++i) {
        const int x  = x0 + i;
        const int fx = x - ((x >= 64) ? N : 0);
        const int s  = isqrt_i(fx * fx + ryz);
        if (s != cs) {
            if (cs >= 0 && cs < NSHELL) {
                atomicAdd(&bins[cs * 3 + 0], w * aC);
                atomicAdd(&bins[cs * 3 + 1], w * aP1);
                atomicAdd(&bins[cs * 3 + 2], w * aP2);
            }
            cs = s; aC = 0.f; aP1 = 0.f; aP2 = 0.f;
        }
        if (s < NSHELL) {
            const int mx = (N - x) & (N - 1);
            const float2 Av = S[x  * TP + l];
            const float2 Bv = S[mx * TP + 8 + l];
            const float F1x = 0.5f * (Av.x + Bv.x);
            const float F1y = 0.5f * (Av.y - Bv.y);
            const float F2x = 0.5f * (Av.y + Bv.y);
            const float F2y = 0.5f * (Bv.x - Av.x);
            aC  += F1x * F2x + F1y * F2y;
            aP1 += F1x * F1x + F1y * F1y;
            aP2 += F2x * F2x + F2y * F2y;
        }
    }
    if (cs >= 0 && cs < NSHELL) {
        atomicAdd(&bins[cs * 3 + 0], w * aC);
        atomicAdd(&bins[cs * 3 + 1], w * aP1);
        atomicAdd(&bins[cs * 3 + 2], w * aP2);
    }
    __syncthreads();

    // replica flush, trimmed to touched shells [smin, 63]
    const int lo = 3 * isqrt_i(fy * fy + z0 * z0);
    float* acc = accum +
        ((size_t)(blockIdx.x & (NREP - 1)) * BTOT + (b0 + bl)) * (NSHELL * 3);
    for (int i = t; i < NSHELL * 3; i += 256) {
        if (i >= lo) atomicAdd(&acc[i], sh[i] + sh[193 + i]);
    }
}

// ---------------------------------------------------------------------------
// Pass 4: FSC + loss. 512 threads = 8 batches x 64 shells; sums NREP replicas.
// ---------------------------------------------------------------------------
__global__ __launch_bounds__(512) void k_final(const float* __restrict__ accum,
                                               float* __restrict__ out) {
    __shared__ float red[8];
    const int tid = threadIdx.x;                 // tid = b*64 + s
    const int b = tid >> 6;
    const int s = tid & 63;
    float num = 0.f, d1 = 0.f, d2 = 0.f;
#pragma unroll 4
    for (int r = 0; r < NREP; ++r) {
        const float* a = accum + ((size_t)r * BTOT + b) * (NSHELL * 3) + s * 3;
        num += a[0]; d1 += a[1]; d2 += a[2];
    }
    const float fsc = num / (sqrtf(d1 * d2) + 1e-8f);
    float v = fsc * fsc;
#pragma unroll
    for (int off = 32; off > 0; off >>= 1) v += __shfl_down(v, off);
    if ((tid & 63) == 0) red[tid >> 6] = v;
    __syncthreads();
    if (tid == 0) {
        float ssum = 0.f;
#pragma unroll
        for (int i = 0; i < 8; ++i) ssum += red[i];
        out[0] = 1.0f - ssum / 512.0f;
    }
}

extern "C" void kernel_launch(void* const* d_in, const int* in_sizes, int n_in,
                              void* d_out, int out_size, void* d_ws, size_t ws_size,
                              hipStream_t stream) {
    const float* ref  = (const float*)d_in[0];
    const float* pred = (const float*)d_in[1];
    float* out = (float*)d_out;

    char*   ws    = (char*)d_ws;
    float*  accum = (float*)ws;                  // NREP*BTOT*192 floats = 192 KiB
    float2* Zbuf  = (float2*)(ws + 262144);

    const size_t zbytes = (size_t)VOL * sizeof(float2);
    int cap = 1;
    if (ws_size > 262144) {
        size_t c = (ws_size - 262144) / zbytes;
        cap = (c < 1) ? 1 : (c > BTOT ? BTOT : (int)c);
    }

    hipMemsetAsync(accum, 0, (size_t)NREP * BTOT * NSHELL * 3 * sizeof(float), stream);

    for (int b0 = 0; b0 < BTOT; b0 += cap) {
        const int nb = (BTOT - b0 < cap) ? (BTOT - b0) : cap;
        const int nblk = nb * 1024;
        k_fftz_pack<<<nblk, 256, 0, stream>>>(ref, pred, Zbuf, b0);
        k_ffty<<<nblk, 256, 0, stream>>>(Zbuf);
        k_fftx_reduce<<<nblk, 256, 0, stream>>>(Zbuf, accum, b0);
    }
    k_final<<<1, 512, 0, stream>>>(accum, out);
}

// Round 9
// 317.581 us; speedup vs baseline: 1.0199x; 1.0023x over previous
//
#include <hip/hip_runtime.h>
#include <math.h>

#define N      128
#define LOGN   7
#define NSQ    (N * N)          // 16384
#define VOL    (N * N * N)      // 2097152
#define NSHELL 64
#define BTOT   8
#define NREP   32               // accumulator replicas
#define FPI    3.14159265358979323846f

#define TP     17               // padded stride, 16-line tile (fftz)
#define TP2    33               // padded stride, 32-line tile (ffty / fftx_reduce)

// ---------------------------------------------------------------------------
// 16-line 128-point in-place Stockham FFT (radix-4 fused + radix-2 tail).
// Verified rounds 5-8. Used by k_fftz_pack.
// ---------------------------------------------------------------------------
__device__ inline void fft16_ip(float2* S, int t) {
    const int j5 = t & 31;
    const int lg = (t >> 5) << 1;
#pragma unroll
    for (int s = 0; s < 6; s += 2) {
        const int Ns = 1 << s;
        const int m  = j5 & (Ns - 1);
        const int cc = j5 >> s;
        const int e0 = (cc << (s + 2)) + m;
        float s2, c2;
        __sincosf(-FPI * (float)m / (float)(2 * Ns), &s2, &c2);
        const float cw = c2 * c2 - s2 * s2;
        const float sw = 2.f * c2 * s2;
        __syncthreads();
        float2 a[2], cv[2], b[2], d[2];
#pragma unroll
        for (int l = 0; l < 2; ++l) {
            a[l]  = S[ j5       * TP + lg + l];
            cv[l] = S[(j5 + 32) * TP + lg + l];
            b[l]  = S[(j5 + 64) * TP + lg + l];
            d[l]  = S[(j5 + 96) * TP + lg + l];
        }
        __syncthreads();
#pragma unroll
        for (int l = 0; l < 2; ++l) {
            const int line = lg + l;
            const float wbx = b[l].x * cw - b[l].y * sw, wby = b[l].x * sw + b[l].y * cw;
            const float wdx = d[l].x * cw - d[l].y * sw, wdy = d[l].x * sw + d[l].y * cw;
            const float Apx = a[l].x + wbx, Apy = a[l].y + wby;
            const float Amx = a[l].x - wbx, Amy = a[l].y - wby;
            const float Bpx = cv[l].x + wdx, Bpy = cv[l].y + wdy;
            const float Bmx = cv[l].x - wdx, Bmy = cv[l].y - wdy;
            const float t0x = Bpx * c2 - Bpy * s2, t0y = Bpx * s2 + Bpy * c2;
            const float t1x = Bmx * c2 - Bmy * s2, t1y = Bmx * s2 + Bmy * c2;
            S[(e0)          * TP + line] = make_float2(Apx + t0x, Apy + t0y);
            S[(e0 + Ns)     * TP + line] = make_float2(Amx + t1y, Amy - t1x);
            S[(e0 + 2 * Ns) * TP + line] = make_float2(Apx - t0x, Apy - t0y);
            S[(e0 + 3 * Ns) * TP + line] = make_float2(Amx - t1y, Amy + t1x);
        }
    }
    {   // final radix-2 stage
        const int m   = t & 63;
        const int grp = (t >> 6) << 2;
        float sw, cw;
        __sincosf(-FPI * (float)m / 64.f, &sw, &cw);
        __syncthreads();
        float2 v0[4], v1[4];
#pragma unroll
        for (int l = 0; l < 4; ++l) {
            v0[l] = S[ m       * TP + grp + l];
            v1[l] = S[(m + 64) * TP + grp + l];
        }
        __syncthreads();
#pragma unroll
        for (int l = 0; l < 4; ++l) {
            const float wx = v1[l].x * cw - v1[l].y * sw;
            const float wy = v1[l].x * sw + v1[l].y * cw;
            S[ m       * TP + grp + l] = make_float2(v0[l].x + wx, v0[l].y + wy);
            S[(m + 64) * TP + grp + l] = make_float2(v0[l].x - wx, v0[l].y - wy);
        }
    }
    __syncthreads();
}

// ---------------------------------------------------------------------------
// 32-line variant (same math; 4 lines/thread in radix-4 stages, 8 in tail).
// Stride TP2 = 33.
// ---------------------------------------------------------------------------
__device__ inline void fft32_ip(float2* S, int t) {
    const int j5 = t & 31;
    const int lg = (t >> 5) << 2;    // 4 lines per thread
#pragma unroll
    for (int s = 0; s < 6; s += 2) {
        const int Ns = 1 << s;
        const int m  = j5 & (Ns - 1);
        const int cc = j5 >> s;
        const int e0 = (cc << (s + 2)) + m;
        float s2, c2;
        __sincosf(-FPI * (float)m / (float)(2 * Ns), &s2, &c2);
        const float cw = c2 * c2 - s2 * s2;
        const float sw = 2.f * c2 * s2;
        __syncthreads();
        float2 a[4], cv[4], b[4], d[4];
#pragma unroll
        for (int l = 0; l < 4; ++l) {
            a[l]  = S[ j5       * TP2 + lg + l];
            cv[l] = S[(j5 + 32) * TP2 + lg + l];
            b[l]  = S[(j5 + 64) * TP2 + lg + l];
            d[l]  = S[(j5 + 96) * TP2 + lg + l];
        }
        __syncthreads();
#pragma unroll
        for (int l = 0; l < 4; ++l) {
            const int line = lg + l;
            const float wbx = b[l].x * cw - b[l].y * sw, wby = b[l].x * sw + b[l].y * cw;
            const float wdx = d[l].x * cw - d[l].y * sw, wdy = d[l].x * sw + d[l].y * cw;
            const float Apx = a[l].x + wbx, Apy = a[l].y + wby;
            const float Amx = a[l].x - wbx, Amy = a[l].y - wby;
            const float Bpx = cv[l].x + wdx, Bpy = cv[l].y + wdy;
            const float Bmx = cv[l].x - wdx, Bmy = cv[l].y - wdy;
            const float t0x = Bpx * c2 - Bpy * s2, t0y = Bpx * s2 + Bpy * c2;
            const float t1x = Bmx * c2 - Bmy * s2, t1y = Bmx * s2 + Bmy * c2;
            S[(e0)          * TP2 + line] = make_float2(Apx + t0x, Apy + t0y);
            S[(e0 + Ns)     * TP2 + line] = make_float2(Amx + t1y, Amy - t1x);
            S[(e0 + 2 * Ns) * TP2 + line] = make_float2(Apx - t0x, Apy - t0y);
            S[(e0 + 3 * Ns) * TP2 + line] = make_float2(Amx - t1y, Amy + t1x);
        }
    }
    {   // final radix-2 stage, 8 lines/thread
        const int m   = t & 63;
        const int grp = (t >> 6) << 3;
        float sw, cw;
        __sincosf(-FPI * (float)m / 64.f, &sw, &cw);
        __syncthreads();
        float2 v0[8], v1[8];
#pragma unroll
        for (int l = 0; l < 8; ++l) {
            v0[l] = S[ m       * TP2 + grp + l];
            v1[l] = S[(m + 64) * TP2 + grp + l];
        }
        __syncthreads();
#pragma unroll
        for (int l = 0; l < 8; ++l) {
            const float wx = v1[l].x * cw - v1[l].y * sw;
            const float wy = v1[l].x * sw + v1[l].y * cw;
            S[ m       * TP2 + grp + l] = make_float2(v0[l].x + wx, v0[l].y + wy);
            S[(m + 64) * TP2 + grp + l] = make_float2(v0[l].x - wx, v0[l].y - wy);
        }
    }
    __syncthreads();
}

// ---------------------------------------------------------------------------
// Pass 1: pack Z = ref + i*pred and FFT along z (contiguous). Unchanged.
// ---------------------------------------------------------------------------
__global__ __launch_bounds__(256) void k_fftz_pack(const float* __restrict__ ref,
                                                   const float* __restrict__ pred,
                                                   float2* __restrict__ Z, int b0) {
    __shared__ float2 S[N * TP];
    const int t  = threadIdx.x;
    const int yt = blockIdx.x & 7;
    const int x  = (blockIdx.x >> 3) & (N - 1);
    const int bl = blockIdx.x >> 10;
    const size_t inbase = (size_t)(b0 + bl) * VOL + (size_t)x * NSQ + (size_t)yt * 16 * N;
    const size_t zbase  = (size_t)bl * VOL + (size_t)x * NSQ + (size_t)yt * 16 * N;
    const float4* r4 = (const float4*)(ref + inbase);
    const float4* p4 = (const float4*)(pred + inbase);
#pragma unroll
    for (int i = 0; i < 2; ++i) {
        const int idx = i * 256 + t;
        const float4 rv = r4[idx];
        const float4 pv = p4[idx];
        const int elem = idx * 4;
        const int z = elem & (N - 1);
        const int j = elem >> LOGN;
        S[(z + 0) * TP + j] = make_float2(rv.x, pv.x);
        S[(z + 1) * TP + j] = make_float2(rv.y, pv.y);
        S[(z + 2) * TP + j] = make_float2(rv.z, pv.z);
        S[(z + 3) * TP + j] = make_float2(rv.w, pv.w);
    }
    fft16_ip(S, t);
    float4* z4 = (float4*)(Z + zbase);
#pragma unroll
    for (int i = 0; i < 4; ++i) {
        const int idx = i * 256 + t;
        const int elem = idx * 2;
        const int z = elem & (N - 1);
        const int j = elem >> LOGN;
        const float2 u0 = S[ z      * TP + j];
        const float2 u1 = S[(z + 1) * TP + j];
        z4[idx] = make_float4(u0.x, u0.y, u1.x, u1.y);
    }
}

// ---------------------------------------------------------------------------
// Pass 2: FFT along y, 32-z tiles (256-B rows -> half the row-reads).
// ---------------------------------------------------------------------------
__global__ __launch_bounds__(256) void k_ffty(float2* __restrict__ Z) {
    __shared__ float2 S[N * TP2];
    const int t   = threadIdx.x;
    const int zt  = blockIdx.x & 3;
    const int mid = (blockIdx.x >> 2) & (N - 1);
    const int bl  = blockIdx.x >> 9;
    const size_t base = (size_t)bl * VOL + (size_t)mid * NSQ + (size_t)zt * 32;
#pragma unroll
    for (int i = 0; i < 8; ++i) {
        const int idx = i * 256 + t;         // 2048 float4: 128 rows x 16
        const int j = idx >> 4;              // y (row)
        const int q = (idx & 15) * 2;        // zz pair
        const float4 v = *(const float4*)&Z[base + (size_t)j * N + q];
        S[j * TP2 + q]     = make_float2(v.x, v.y);
        S[j * TP2 + q + 1] = make_float2(v.z, v.w);
    }
    fft32_ip(S, t);
#pragma unroll
    for (int i = 0; i < 8; ++i) {
        const int idx = i * 256 + t;
        const int j = idx >> 4;
        const int q = (idx & 15) * 2;
        const float2 u0 = S[j * TP2 + q];
        const float2 u1 = S[j * TP2 + q + 1];
        *(float4*)&Z[base + (size_t)j * N + q] = make_float4(u0.x, u0.y, u1.x, u1.y);
    }
}

// ---------------------------------------------------------------------------
// Exact floor(sqrt(r2)) for integer r2.
// ---------------------------------------------------------------------------
__device__ inline int isqrt_i(int r2) {
    int s = (int)sqrtf((float)r2);
    s -= (s * s > r2);
    s += ((s + 1) * (s + 1) <= r2);
    return s;
}

// ---------------------------------------------------------------------------
// Pass 3 (fused): x-FFT + Hermitian-pair shell reduction, 16-z tiles.
// Block = (batch, y, z0 in {0,16,32,48}). LDS lines 0..15 = A (y, z0+zz);
// lines 16..31 = partners (my, (128-z0-zz)&127). 128-B rows halve the
// row-read count vs round 6-8 (the measured ~55 ns/row-read limiter).
// Weights: z=64 plane dropped (s>=64); z in [1,63] w=2; z=0 w=1 (r6-verified).
// ---------------------------------------------------------------------------
__global__ __launch_bounds__(256) void k_fftx_reduce(const float2* __restrict__ Z,
                                                     float* __restrict__ accum, int b0) {
    const int t  = threadIdx.x;
    const int zr = blockIdx.x & 3;
    const int y  = (blockIdx.x >> 2) & (N - 1);
    const int bl = blockIdx.x >> 9;
    const int z0 = zr * 16;
    const int fy = y - ((y >= 64) ? N : 0);

    if (fy * fy + z0 * z0 >= 4096) return;   // whole tile outside sphere

    __shared__ float2 S[N * TP2];
    __shared__ float sh[2 * 193];
    for (int i = t; i < 2 * 193; i += 256) sh[i] = 0.f;
    // (visibility guaranteed by syncs inside fft32_ip)

    const int my = (N - y) & (N - 1);
    const size_t zb    = (size_t)bl * VOL;
    const size_t baseA = zb + (size_t)y  * N + z0;
    const size_t baseB = zb + (size_t)my * N;
#pragma unroll
    for (int i = 0; i < 4; ++i) {            // A: 128 rows x 8 float4 (128 B)
        const int idx = i * 256 + t;
        const int j = idx >> 3;              // x row
        const int q = (idx & 7) * 2;         // zz pair in [0,16)
        const float4 v = *(const float4*)&Z[baseA + (size_t)j * NSQ + q];
        S[j * TP2 + q]     = make_float2(v.x, v.y);
        S[j * TP2 + q + 1] = make_float2(v.z, v.w);
    }
#pragma unroll
    for (int i = 0; i < 8; ++i) {            // B: 128 rows x 16 float2 (rev)
        const int elem = i * 256 + t;
        const int zz = elem & 15;
        const int j  = elem >> 4;
        const int mz = (N - z0 - zz) & (N - 1);
        S[j * TP2 + 16 + zz] = Z[baseB + (size_t)j * NSQ + mz];
    }

    fft32_ip(S, t);

    // reduce: thread -> z-line l = t>>4 (0..15), x = x0..x0+7 run-length
    const int l  = t >> 4;
    const int x0 = (t & 15) * 8;
    const int z  = z0 + l;                   // fz = z (z <= 63)
    const float w = (z == 0) ? 1.f : 2.f;
    const int ryz = fy * fy + z * z;
    float* bins = sh + (t & 1) * 193;

    float aC = 0.f, aP1 = 0.f, aP2 = 0.f;
    int cs = -1;
#pragma unroll
    for (int i = 0; i < 8; ++i) {
        const int x  = x0 + i;
        const int fx = x - ((x >= 64) ? N : 0);
        const int s  = isqrt_i(fx * fx + ryz);
        if (s != cs) {
            if (cs >= 0 && cs < NSHELL) {
                atomicAdd(&bins[cs * 3 + 0], w * aC);
                atomicAdd(&bins[cs * 3 + 1], w * aP1);
                atomicAdd(&bins[cs * 3 + 2], w * aP2);
            }
            cs = s; aC = 0.f; aP1 = 0.f; aP2 = 0.f;
        }
        if (s < NSHELL) {
            const int mx = (N - x) & (N - 1);
            const float2 Av = S[x  * TP2 + l];
            const float2 Bv = S[mx * TP2 + 16 + l];
            const float F1x = 0.5f * (Av.x + Bv.x);
            const float F1y = 0.5f * (Av.y - Bv.y);
            const float F2x = 0.5f * (Av.y + Bv.y);
            const float F2y = 0.5f * (Bv.x - Av.x);
            aC  += F1x * F2x + F1y * F2y;
            aP1 += F1x * F1x + F1y * F1y;
            aP2 += F2x * F2x + F2y * F2y;
        }
    }
    if (cs >= 0 && cs < NSHELL) {
        atomicAdd(&bins[cs * 3 + 0], w * aC);
        atomicAdd(&bins[cs * 3 + 1], w * aP1);
        atomicAdd(&bins[cs * 3 + 2], w * aP2);
    }
    __syncthreads();

    // replica flush, trimmed to touched shells [smin, 63]
    const int lo = 3 * isqrt_i(fy * fy + z0 * z0);
    float* acc = accum +
        ((size_t)(blockIdx.x & (NREP - 1)) * BTOT + (b0 + bl)) * (NSHELL * 3);
    for (int i = t; i < NSHELL * 3; i += 256) {
        if (i >= lo) atomicAdd(&acc[i], sh[i] + sh[193 + i]);
    }
}

// ---------------------------------------------------------------------------
// Pass 4: FSC + loss. 512 threads = 8 batches x 64 shells; sums NREP replicas.
// ---------------------------------------------------------------------------
__global__ __launch_bounds__(512) void k_final(const float* __restrict__ accum,
                                               float* __restrict__ out) {
    __shared__ float red[8];
    const int tid = threadIdx.x;
    const int b = tid >> 6;
    const int s = tid & 63;
    float num = 0.f, d1 = 0.f, d2 = 0.f;
#pragma unroll 4
    for (int r = 0; r < NREP; ++r) {
        const float* a = accum + ((size_t)r * BTOT + b) * (NSHELL * 3) + s * 3;
        num += a[0]; d1 += a[1]; d2 += a[2];
    }
    const float fsc = num / (sqrtf(d1 * d2) + 1e-8f);
    float v = fsc * fsc;
#pragma unroll
    for (int off = 32; off > 0; off >>= 1) v += __shfl_down(v, off);
    if ((tid & 63) == 0) red[tid >> 6] = v;
    __syncthreads();
    if (tid == 0) {
        float ssum = 0.f;
#pragma unroll
        for (int i = 0; i < 8; ++i) ssum += red[i];
        out[0] = 1.0f - ssum / 512.0f;
    }
}

extern "C" void kernel_launch(void* const* d_in, const int* in_sizes, int n_in,
                              void* d_out, int out_size, void* d_ws, size_t ws_size,
                              hipStream_t stream) {
    const float* ref  = (const float*)d_in[0];
    const float* pred = (const float*)d_in[1];
    float* out = (float*)d_out;

    char*   ws    = (char*)d_ws;
    float*  accum = (float*)ws;                  // NREP*BTOT*192 floats
    float2* Zbuf  = (float2*)(ws + 262144);

    const size_t zbytes = (size_t)VOL * sizeof(float2);
    int cap = 1;
    if (ws_size > 262144) {
        size_t c = (ws_size - 262144) / zbytes;
        cap = (c < 1) ? 1 : (c > BTOT ? BTOT : (int)c);
    }

    hipMemsetAsync(accum, 0, (size_t)NREP * BTOT * NSHELL * 3 * sizeof(float), stream);

    for (int b0 = 0; b0 < BTOT; b0 += cap) {
        const int nb = (BTOT - b0 < cap) ? (BTOT - b0) : cap;
        k_fftz_pack<<<nb * 1024, 256, 0, stream>>>(ref, pred, Zbuf, b0);
        k_ffty<<<nb * 512, 256, 0, stream>>>(Zbuf);
        k_fftx_reduce<<<nb * 512, 256, 0, stream>>>(Zbuf, accum, b0);
    }
    k_final<<<1, 512, 0, stream>>>(accum, out);
}